// Round 13
// baseline (66.211 us; speedup 1.0000x reference)
//
#include <hip/hip_runtime.h>
#include <math.h>

#define B_  32
#define S_  512
#define D_  256
#define H_  4
#define DK_ 64

typedef float  f32x4 __attribute__((ext_vector_type(4)));
typedef short  s16x8 __attribute__((ext_vector_type(8)));
typedef unsigned short u16x4 __attribute__((ext_vector_type(4)));
typedef unsigned int   u32x2 __attribute__((ext_vector_type(2)));
typedef unsigned int   u32x4 __attribute__((ext_vector_type(4)));

#define MFMA_BF16(a, b, c) __builtin_amdgcn_mfma_f32_16x16x32_bf16((a), (b), (c), 0, 0, 0)
#define GLOAD_LDS16(g, l)                                                      \
  __builtin_amdgcn_global_load_lds(                                            \
      (const __attribute__((address_space(1))) void*)(g),                      \
      (__attribute__((address_space(3))) void*)(l), 16, 0, 0)

#if __has_builtin(__builtin_amdgcn_exp2f)
#define EXP2(x) __builtin_amdgcn_exp2f(x)
#else
#define EXP2(x) __expf((x) * 0.6931471805599453f)
#endif

// 0.125 * log2(e): folded into Wq/bq so QK^T lands in log2 domain.
#define QSCALE 0.18033688011112042f

__device__ __forceinline__ unsigned short f2bf(float x) {
  unsigned int u = __float_as_uint(x);
  unsigned int r = (u + 0x7FFFu + ((u >> 16) & 1u)) >> 16;
  return (unsigned short)r;
}

__device__ __forceinline__ float bf2f(unsigned short u) {
  return __uint_as_float((unsigned int)u << 16);
}

__device__ __forceinline__ unsigned cvtpk(float lo, float hi) {
  unsigned r;
  asm("v_cvt_pk_bf16_f32 %0, %1, %2" : "=v"(r) : "v"(lo), "v"(hi));
  return r;
}

// f32x8 -> bf16x8 via 4 cvt_pk (replaces 16 manual-RNE f2bf ops)
__device__ __forceinline__ s16x8 cvt8(const float* p) {
  float4 a = *(const float4*)p;
  float4 b = *(const float4*)(p + 4);
  u32x4 pk;
  pk[0] = cvtpk(a.x, a.y);
  pk[1] = cvtpk(a.z, a.w);
  pk[2] = cvtpk(b.x, b.y);
  pk[3] = cvtpk(b.z, b.w);
  return *(s16x8*)&pk;
}

// ---------------------------------------------------------------------------
// Weights -> bf16: rows 0..255 Wq (pre-scaled by QSCALE), 256..511 Wk,
// 512..575 Wv; Wh at 147456 (pre-scaled by 0.25 for the head-mean fold).
// ---------------------------------------------------------------------------
__global__ void wconv_kernel(const float* __restrict__ Wq, const float* __restrict__ Wk,
                             const float* __restrict__ Wv, const float* __restrict__ Wh,
                             unsigned short* __restrict__ out) {
  int i = blockIdx.x * 256 + threadIdx.x;  // 163840 total
  float v, sc = 1.f;
  if (i < 65536)        { v = Wq[i];          sc = QSCALE; }
  else if (i < 131072)  { v = Wk[i - 65536]; }
  else if (i < 147456)  { v = Wv[i - 131072]; }
  else                  { v = Wh[i - 147456]; sc = 0.25f; }
  out[i] = f2bf(v * sc);
}

// ---------------------------------------------------------------------------
// Fused QKV projection, bf16 MFMA, W k-slice staged in LDS.
// 128 rows / 8 waves per block (halves W-staging + barriers per work);
// all f32->bf16 rounding via v_cvt_pk_bf16_f32.
// ---------------------------------------------------------------------------
__global__ __launch_bounds__(512) void proj_kernel(
    const float* __restrict__ q, const float* __restrict__ k, const float* __restrict__ v,
    const unsigned short* __restrict__ Wb,
    const float* __restrict__ bq, const float* __restrict__ bk, const float* __restrict__ bv,
    unsigned short* __restrict__ qs, unsigned short* __restrict__ ks,
    unsigned short* __restrict__ vst) {
  const int y = blockIdx.y;
  const int m0 = blockIdx.x * 128;
  const int b = m0 >> 9, s0 = m0 & (S_ - 1);
  const int tid = threadIdx.x, w = tid >> 6, l = tid & 63;
  const int lr = l & 15, lg = l >> 4;
  const float* src = (y == 0) ? q : (y == 1) ? k : v;
  const float* abase = src + (size_t)(m0 + w * 16 + lr) * D_;

  __shared__ __align__(16) unsigned short Wsl[16384];  // up to 256 rows x 64 cols bf16

  const int nrows = (y < 2) ? 256 : 64;
  const unsigned short* wbase = Wb + (size_t)(y * 256) * D_;  // y==2 -> rows 512.. (Wv)

  auto stW = [&](int k0) {
    const int nbytes = nrows * 128;
    for (int p = tid * 16; p < nbytes; p += 8192) {
      int row = p >> 7, c = (p >> 4) & 7;
      GLOAD_LDS16((const char*)(wbase + (size_t)row * D_ + k0) + ((c ^ (row & 7)) << 4),
                  (char*)Wsl + p);
    }
  };
  auto WF = [&](int row, int c) -> s16x8 {
    return *(const s16x8*)((const char*)Wsl + row * 128 + ((c ^ (row & 7)) << 4));
  };

  if (y < 2) {
    f32x4 acc[4][4] = {};
    for (int k0 = 0; k0 < D_; k0 += 64) {
      stW(k0);
      s16x8 af0 = cvt8(abase + k0 + 8 * lg);
      s16x8 af1 = cvt8(abase + k0 + 32 + 8 * lg);
      __syncthreads();
#pragma unroll
      for (int h = 0; h < 4; ++h) {
#pragma unroll
        for (int ns = 0; ns < 4; ++ns) {
          s16x8 wf0 = WF(h * 64 + ns * 16 + lr, lg);
          s16x8 wf1 = WF(h * 64 + ns * 16 + lr, 4 + lg);
          acc[h][ns] = MFMA_BF16(af0, wf0, acc[h][ns]);
          acc[h][ns] = MFMA_BF16(af1, wf1, acc[h][ns]);
        }
      }
      __syncthreads();
    }
    const float* bias = (y == 0) ? bq : bk;
    const float bsc = (y == 0) ? QSCALE : 1.f;
    unsigned short* dst = (y == 0) ? qs : ks;
#pragma unroll
    for (int h = 0; h < 4; ++h) {
#pragma unroll
      for (int ns = 0; ns < 4; ++ns) {
        int dk = ns * 16 + lr;
        float bb = bias[h * 64 + dk] * bsc;
        unsigned u0 = cvtpk(acc[h][ns][0] + bb, acc[h][ns][1] + bb);
        unsigned u1 = cvtpk(acc[h][ns][2] + bb, acc[h][ns][3] + bb);
        size_t base = (((size_t)b * H_ + h) * S_ + s0 + w * 16 + lg * 4) * DK_ + dk;
        dst[base]            = (unsigned short)u0;
        dst[base + DK_]      = (unsigned short)(u0 >> 16);
        dst[base + 2 * DK_]  = (unsigned short)u1;
        dst[base + 3 * DK_]  = (unsigned short)(u1 >> 16);
      }
    }
  } else {
    f32x4 acc[4] = {};
    for (int k0 = 0; k0 < D_; k0 += 64) {
      stW(k0);
      s16x8 af0 = cvt8(abase + k0 + 8 * lg);
      s16x8 af1 = cvt8(abase + k0 + 32 + 8 * lg);
      __syncthreads();
#pragma unroll
      for (int ns = 0; ns < 4; ++ns) {
        s16x8 wf0 = WF(ns * 16 + lr, lg);
        s16x8 wf1 = WF(ns * 16 + lr, 4 + lg);
        acc[ns] = MFMA_BF16(af0, wf0, acc[ns]);
        acc[ns] = MFMA_BF16(af1, wf1, acc[ns]);
      }
      __syncthreads();
    }
#pragma unroll
    for (int ns = 0; ns < 4; ++ns) {
      int dk = ns * 16 + lr;
      float bb = bv[dk];
      u32x2 pk2;
      pk2[0] = cvtpk(acc[ns][0] + bb, acc[ns][1] + bb);
      pk2[1] = cvtpk(acc[ns][2] + bb, acc[ns][3] + bb);
      int t = s0 + w * 16 + lg * 4;
      *(u16x4*)(vst + ((size_t)b * DK_ + dk) * S_ + t) = *(u16x4*)&pk2;
    }
  }
}

// ---------------------------------------------------------------------------
// SINGLE-PASS fused scores + softmax + attn-write + PV + causal zerofill
// (r12 structure, unchanged).
// ---------------------------------------------------------------------------
__global__ __launch_bounds__(512) void attn_kernel(
    const unsigned short* __restrict__ qs, const unsigned short* __restrict__ ks,
    const unsigned short* __restrict__ vst, float* __restrict__ attn,
    unsigned short* __restrict__ hh) {
  const int m = blockIdx.x;
  const int half = m >> 8, g = (m >> 1) & 1;
  const int stp = half ? (3 - g) : g;                  // s-strip 0..3 (128 rows)
  const int rem = ((m >> 2) & 63) * 2 + (m & 1);       // 0..127
  const int b = rem & 31, h = rem >> 5;
  const int tid = threadIdx.x, w = tid >> 6, l = tid & 63;
  const int lr = l & 15, lg = l >> 4;
  const int S0 = stp * 128;
  const int dtile = 2 * stp + (w >> 2);                // this wave's diag t-tile
  const int NT = 2 * stp + 2;                          // t-tiles staged per block
  const int sg = S0 + w * 16 + lr;                     // this lane's s row (fixed)

  __shared__ __align__(16) unsigned short Kb[2][4096];   // 64x64 bf16, swizzled
  __shared__ __align__(16) unsigned short Vb[2][4096];   // [dk][t] bf16, swizzled
  __shared__ __align__(16) unsigned short Pb[8][16][72]; // per-wave P, [s][t]+pad

  const unsigned short* qb = qs + ((size_t)b * H_ + h) * S_ * DK_;
  const char* kbase = (const char*)(ks + ((size_t)b * H_ + h) * S_ * DK_);
  const char* vbase = (const char*)(vst + (size_t)b * DK_ * S_);

  auto stK = [&](int buf, int t0) {
    int p = tid * 16;
    int row = p >> 7, c = (p >> 4) & 7;
    GLOAD_LDS16(kbase + (size_t)t0 * 128 + row * 128 + ((c ^ (row & 7)) << 4),
                (char*)&Kb[buf][0] + p);
  };
  auto stV = [&](int buf, int t0) {
    int p = tid * 16;
    int row = p >> 7, c = (p >> 4) & 7;
    GLOAD_LDS16(vbase + (size_t)row * 1024 + t0 * 2 + ((c ^ (row & 7)) << 4),
                (char*)&Vb[buf][0] + p);
  };
  auto KF = [&](int buf, int row, int c) -> s16x8 {
    return *(const s16x8*)((const char*)&Kb[buf][0] + row * 128 + ((c ^ (row & 7)) << 4));
  };
  auto VF = [&](int buf, int row, int c) -> s16x8 {
    return *(const s16x8*)((const char*)&Vb[buf][0] + row * 128 + ((c ^ (row & 7)) << 4));
  };

  s16x8 qf0 = *(const s16x8*)(qb + (size_t)sg * DK_ + 8 * lg);
  s16x8 qf1 = *(const s16x8*)(qb + (size_t)sg * DK_ + 32 + 8 * lg);

  float ls[4] = {0.f, 0.f, 0.f, 0.f};
  unsigned preg[8][8];   // packed bf16 p' per tile; statically indexed
  f32x4 oacc[4] = {};

  // ---- single staged pass: QK^T once, p' packed, PV unnormalized ----
  stK(0, 0);
  stV(0, 0);
  __syncthreads();
#pragma unroll
  for (int tt = 0; tt < 8; ++tt) {
    if (tt >= NT) continue;                  // block-uniform
    const int t0 = tt * 64;
    const int cur = tt & 1;
    if (tt + 1 < NT) { stK(cur ^ 1, t0 + 64); stV(cur ^ 1, t0 + 64); }
    if (tt <= dtile) {
#pragma unroll
      for (int ts = 0; ts < 4; ++ts) {
        s16x8 kf0 = KF(cur, ts * 16 + lr, lg);
        s16x8 kf1 = KF(cur, ts * 16 + lr, 4 + lg);
        f32x4 acc = {};
        acc = MFMA_BF16(kf0, qf0, acc);   // swapped: lane holds s=lr, t=tb+i
        acc = MFMA_BF16(kf1, qf1, acc);
        const int tb = t0 + ts * 16 + 4 * lg;
        float p[4];
        if (tt == dtile) {
#pragma unroll
          for (int i = 0; i < 4; ++i) p[i] = EXP2((tb + i > sg) ? -1e30f : acc[i]);
        } else {
#pragma unroll
          for (int i = 0; i < 4; ++i) p[i] = EXP2(acc[i]);
        }
        ls[ts] += (p[0] + p[1]) + (p[2] + p[3]);
        unsigned pk0 = cvtpk(p[0], p[1]);
        unsigned pk1 = cvtpk(p[2], p[3]);
        preg[tt][ts * 2] = pk0;
        preg[tt][ts * 2 + 1] = pk1;
        *(u32x2*)&Pb[w][lr][ts * 16 + 4 * lg] = *(u32x2*)&preg[tt][ts * 2];
      }
      asm volatile("s_waitcnt lgkmcnt(0)" ::: "memory");
      __builtin_amdgcn_sched_barrier(0);
      s16x8 pa0 = *(const s16x8*)(&Pb[w][lr][8 * lg]);
      s16x8 pa1 = *(const s16x8*)(&Pb[w][lr][32 + 8 * lg]);
#pragma unroll
      for (int ds = 0; ds < 4; ++ds) {
        s16x8 vf0 = VF(cur, ds * 16 + lr, lg);
        s16x8 vf1 = VF(cur, ds * 16 + lr, 4 + lg);
        oacc[ds] = MFMA_BF16(pa0, vf0, oacc[ds]);
        oacc[ds] = MFMA_BF16(pa1, vf1, oacc[ds]);
      }
    }
    __syncthreads();
  }

  // ---- reduce row sum (lane-local row s=lr) ----
  float lsum = (ls[0] + ls[1]) + (ls[2] + ls[3]);
  lsum += __shfl_xor(lsum, 16);
  lsum += __shfl_xor(lsum, 32);
  const float inv = 1.0f / lsum;

  // ---- phase B: normalized attn writes (pure streaming, no barriers) ----
#pragma unroll
  for (int tt = 0; tt < 8; ++tt) {
    if (tt <= dtile) {
      const int t0 = tt * 64;
#pragma unroll
      for (int ts = 0; ts < 4; ++ts) {
        unsigned a = preg[tt][ts * 2], c2 = preg[tt][ts * 2 + 1];
        f32x4 p;
        p[0] = bf2f((unsigned short)a) * inv;
        p[1] = bf2f((unsigned short)(a >> 16)) * inv;
        p[2] = bf2f((unsigned short)c2) * inv;
        p[3] = bf2f((unsigned short)(c2 >> 16)) * inv;
        const int tb = t0 + ts * 16 + 4 * lg;
        *(f32x4*)(attn + (((size_t)b * S_ + sg) * H_ + h) * S_ + tb) = p;
      }
    }
  }

  // ---- causal zerofill above this wave's diagonal tile ----
  for (int tt = dtile + 1; tt < 8; ++tt) {
    const int t0 = tt * 64;
    f32x4 z = {};
#pragma unroll
    for (int i = 0; i < 4; ++i) {
      int sr = S0 + w * 16 + lg * 4 + i;
      *(f32x4*)(attn + (((size_t)b * S_ + sr) * H_ + h) * S_ + t0 + lr * 4) = z;
    }
  }

  // ---- per-head output: scale by shfl-gathered inv, write bf16 ----
  float invO[4];
#pragma unroll
  for (int i = 0; i < 4; ++i) invO[i] = __shfl(inv, lg * 4 + i);
#pragma unroll
  for (int ds = 0; ds < 4; ++ds) {
#pragma unroll
    for (int i = 0; i < 4; ++i) {
      int s = S0 + w * 16 + lg * 4 + i;
      hh[(((size_t)b * H_ + h) * S_ + s) * DK_ + ds * 16 + lr] = f2bf(oacc[ds][i] * invO[i]);
    }
  }
}

// ---------------------------------------------------------------------------
// Fused head-mean + output projection: ONE block per 64-row m-panel, full
// N=256.  Full Wh (32 KB) staged once; head-mean af computed once (was 4x).
// ---------------------------------------------------------------------------
__global__ __launch_bounds__(256) void houtproj_kernel(
    const unsigned short* __restrict__ hh, const unsigned short* __restrict__ Whb,
    float* __restrict__ out) {
  const int m0 = blockIdx.x * 64;
  const int tid = threadIdx.x, w = tid >> 6, l = tid & 63;
  const int lr = l & 15, lg = l >> 4;
  const int row = m0 + w * 16 + lr;
  const int b = row >> 9, s = row & (S_ - 1);

  __shared__ __align__(16) unsigned short Whs[16384];  // 256 x 64 bf16

#pragma unroll
  for (int it = 0; it < 8; ++it) {
    int p = it * 4096 + tid * 16;
    int r = p >> 7, c = (p >> 4) & 7;
    GLOAD_LDS16((const char*)(Whb + (size_t)r * DK_) + ((c ^ (r & 7)) << 4),
                (char*)Whs + p);
  }

  s16x8 af[2];
#pragma unroll
  for (int kk = 0; kk < 2; ++kk) {
    float sum8[8] = {};
#pragma unroll
    for (int hd = 0; hd < 4; ++hd) {
      s16x8 x = *(const s16x8*)(hh + (((size_t)b * H_ + hd) * S_ + s) * DK_ + kk * 32 + 8 * lg);
#pragma unroll
      for (int e = 0; e < 8; ++e) sum8[e] += bf2f((unsigned short)x[e]);
    }
    u32x4 pk;
#pragma unroll
    for (int j = 0; j < 4; ++j) pk[j] = cvtpk(sum8[2 * j], sum8[2 * j + 1]);
    af[kk] = *(s16x8*)&pk;
  }
  __syncthreads();

  auto WHF = [&](int r, int c) -> s16x8 {
    return *(const s16x8*)((const char*)Whs + r * 128 + ((c ^ (r & 7)) << 4));
  };
#pragma unroll
  for (int np = 0; np < 4; ++np) {
    f32x4 acc[4] = {};
#pragma unroll
    for (int ns = 0; ns < 4; ++ns) {
      s16x8 wf0 = WHF(np * 64 + ns * 16 + lr, lg);
      s16x8 wf1 = WHF(np * 64 + ns * 16 + lr, 4 + lg);
      acc[ns] = MFMA_BF16(af[0], wf0, acc[ns]);
      acc[ns] = MFMA_BF16(af[1], wf1, acc[ns]);
    }
#pragma unroll
    for (int ns = 0; ns < 4; ++ns) {
#pragma unroll
      for (int i = 0; i < 4; ++i) {
        out[(size_t)(m0 + w * 16 + lg * 4 + i) * D_ + np * 64 + ns * 16 + lr] = acc[ns][i];
      }
    }
  }
}

// ---------------------------------------------------------------------------
extern "C" void kernel_launch(void* const* d_in, const int* in_sizes, int n_in,
                              void* d_out, int out_size, void* d_ws, size_t ws_size,
                              hipStream_t stream) {
  (void)in_sizes; (void)n_in; (void)out_size; (void)ws_size;
  const float* q  = (const float*)d_in[0];
  const float* k  = (const float*)d_in[1];
  const float* v  = (const float*)d_in[2];
  const float* Wq = (const float*)d_in[4];
  const float* bq = (const float*)d_in[5];
  const float* Wk = (const float*)d_in[6];
  const float* bk = (const float*)d_in[7];
  const float* Wv = (const float*)d_in[8];
  const float* bv = (const float*)d_in[9];
  const float* Wh = (const float*)d_in[10];

  float* out  = (float*)d_out;                       // [B,S,D]
  float* attn = out + (size_t)B_ * S_ * D_;          // [B,S,H,S]

  char* ws = (char*)d_ws;
  unsigned short* Wb  = (unsigned short*)ws;                         // 163840 elems
  unsigned short* qs  = (unsigned short*)(ws + 327680);              // [B,H,S,DK] bf16
  unsigned short* ksp = (unsigned short*)(ws + 327680 + 8388608);    // [B,H,S,DK] bf16
  unsigned short* vst = (unsigned short*)(ws + 327680 + 16777216);   // [B,DK,S]  bf16
  unsigned short* hh  = (unsigned short*)(ws + 327680 + 18874368);   // [B,H,S,DK] bf16

  wconv_kernel<<<640, 256, 0, stream>>>(Wq, Wk, Wv, Wh, Wb);
  proj_kernel<<<dim3(128, 3), 512, 0, stream>>>(q, k, v, Wb, bq, bk, bv, qs, ksp, vst);
  attn_kernel<<<512, 512, 0, stream>>>(qs, ksp, vst, attn, hh);
  houtproj_kernel<<<256, 256, 0, stream>>>(hh, Wb + 147456, out);
}

// Round 14
// 61.869 us; speedup vs baseline: 1.0702x; 1.0702x over previous
//
#include <hip/hip_runtime.h>
#include <math.h>

#define B_  32
#define S_  512
#define D_  256
#define H_  4
#define DK_ 64

typedef float  f32x4 __attribute__((ext_vector_type(4)));
typedef short  s16x8 __attribute__((ext_vector_type(8)));
typedef unsigned short u16x4 __attribute__((ext_vector_type(4)));
typedef unsigned int   u32x2 __attribute__((ext_vector_type(2)));
typedef unsigned int   u32x4 __attribute__((ext_vector_type(4)));

#define MFMA_BF16(a, b, c) __builtin_amdgcn_mfma_f32_16x16x32_bf16((a), (b), (c), 0, 0, 0)
#define GLOAD_LDS16(g, l)                                                      \
  __builtin_amdgcn_global_load_lds(                                            \
      (const __attribute__((address_space(1))) void*)(g),                      \
      (__attribute__((address_space(3))) void*)(l), 16, 0, 0)

#if __has_builtin(__builtin_amdgcn_exp2f)
#define EXP2(x) __builtin_amdgcn_exp2f(x)
#else
#define EXP2(x) __expf((x) * 0.6931471805599453f)
#endif

// 0.125 * log2(e): folded into Wq/bq so QK^T lands in log2 domain.
#define QSCALE 0.18033688011112042f

__device__ __forceinline__ unsigned short f2bf(float x) {
  unsigned int u = __float_as_uint(x);
  unsigned int r = (u + 0x7FFFu + ((u >> 16) & 1u)) >> 16;
  return (unsigned short)r;
}

__device__ __forceinline__ float bf2f(unsigned short u) {
  return __uint_as_float((unsigned int)u << 16);
}

__device__ __forceinline__ unsigned cvtpk(float lo, float hi) {
  unsigned r;
  asm("v_cvt_pk_bf16_f32 %0, %1, %2" : "=v"(r) : "v"(lo), "v"(hi));
  return r;
}

// f32x8 -> bf16x8 via 4 cvt_pk (replaces 16 manual-RNE f2bf ops)
__device__ __forceinline__ s16x8 cvt8(const float* p) {
  float4 a = *(const float4*)p;
  float4 b = *(const float4*)(p + 4);
  u32x4 pk;
  pk[0] = cvtpk(a.x, a.y);
  pk[1] = cvtpk(a.z, a.w);
  pk[2] = cvtpk(b.x, b.y);
  pk[3] = cvtpk(b.z, b.w);
  return *(s16x8*)&pk;
}

// ---------------------------------------------------------------------------
// Weights -> bf16: rows 0..255 Wq (pre-scaled by QSCALE), 256..511 Wk,
// 512..575 Wv; Wh at 147456 (pre-scaled by 0.25 for the head-mean fold).
// ---------------------------------------------------------------------------
__global__ void wconv_kernel(const float* __restrict__ Wq, const float* __restrict__ Wk,
                             const float* __restrict__ Wv, const float* __restrict__ Wh,
                             unsigned short* __restrict__ out) {
  int i = blockIdx.x * 256 + threadIdx.x;  // 163840 total
  float v, sc = 1.f;
  if (i < 65536)        { v = Wq[i];          sc = QSCALE; }
  else if (i < 131072)  { v = Wk[i - 65536]; }
  else if (i < 147456)  { v = Wv[i - 131072]; }
  else                  { v = Wh[i - 147456]; sc = 0.25f; }
  out[i] = f2bf(v * sc);
}

// ---------------------------------------------------------------------------
// Fused QKV projection, bf16 MFMA, W k-slice staged in LDS.
// r12 grid structure (64 rows / 256 threads, 768 blocks = 3/CU exact);
// f32->bf16 rounding via v_cvt_pk_bf16_f32 (kept from r13).
// ---------------------------------------------------------------------------
__global__ __launch_bounds__(256) void proj_kernel(
    const float* __restrict__ q, const float* __restrict__ k, const float* __restrict__ v,
    const unsigned short* __restrict__ Wb,
    const float* __restrict__ bq, const float* __restrict__ bk, const float* __restrict__ bv,
    unsigned short* __restrict__ qs, unsigned short* __restrict__ ks,
    unsigned short* __restrict__ vst) {
  const int y = blockIdx.y;
  const int m0 = blockIdx.x * 64;
  const int b = m0 >> 9, s0 = m0 & (S_ - 1);
  const int tid = threadIdx.x, w = tid >> 6, l = tid & 63;
  const int lr = l & 15, lg = l >> 4;
  const float* src = (y == 0) ? q : (y == 1) ? k : v;
  const float* abase = src + (size_t)(m0 + w * 16 + lr) * D_;

  __shared__ __align__(16) unsigned short Wsl[16384];  // up to 256 rows x 64 cols bf16

  const int nrows = (y < 2) ? 256 : 64;
  const unsigned short* wbase = Wb + (size_t)(y * 256) * D_;  // y==2 -> rows 512.. (Wv)

  auto stW = [&](int k0) {
    const int nbytes = nrows * 128;
    for (int p = tid * 16; p < nbytes; p += 4096) {
      int row = p >> 7, c = (p >> 4) & 7;
      GLOAD_LDS16((const char*)(wbase + (size_t)row * D_ + k0) + ((c ^ (row & 7)) << 4),
                  (char*)Wsl + p);
    }
  };
  auto WF = [&](int row, int c) -> s16x8 {
    return *(const s16x8*)((const char*)Wsl + row * 128 + ((c ^ (row & 7)) << 4));
  };

  if (y < 2) {
    f32x4 acc[4][4] = {};
    for (int k0 = 0; k0 < D_; k0 += 64) {
      stW(k0);
      s16x8 af0 = cvt8(abase + k0 + 8 * lg);
      s16x8 af1 = cvt8(abase + k0 + 32 + 8 * lg);
      __syncthreads();
#pragma unroll
      for (int h = 0; h < 4; ++h) {
#pragma unroll
        for (int ns = 0; ns < 4; ++ns) {
          s16x8 wf0 = WF(h * 64 + ns * 16 + lr, lg);
          s16x8 wf1 = WF(h * 64 + ns * 16 + lr, 4 + lg);
          acc[h][ns] = MFMA_BF16(af0, wf0, acc[h][ns]);
          acc[h][ns] = MFMA_BF16(af1, wf1, acc[h][ns]);
        }
      }
      __syncthreads();
    }
    const float* bias = (y == 0) ? bq : bk;
    const float bsc = (y == 0) ? QSCALE : 1.f;
    unsigned short* dst = (y == 0) ? qs : ks;
#pragma unroll
    for (int h = 0; h < 4; ++h) {
#pragma unroll
      for (int ns = 0; ns < 4; ++ns) {
        int dk = ns * 16 + lr;
        float bb = bias[h * 64 + dk] * bsc;
        unsigned u0 = cvtpk(acc[h][ns][0] + bb, acc[h][ns][1] + bb);
        unsigned u1 = cvtpk(acc[h][ns][2] + bb, acc[h][ns][3] + bb);
        size_t base = (((size_t)b * H_ + h) * S_ + s0 + w * 16 + lg * 4) * DK_ + dk;
        dst[base]            = (unsigned short)u0;
        dst[base + DK_]      = (unsigned short)(u0 >> 16);
        dst[base + 2 * DK_]  = (unsigned short)u1;
        dst[base + 3 * DK_]  = (unsigned short)(u1 >> 16);
      }
    }
  } else {
    f32x4 acc[4] = {};
    for (int k0 = 0; k0 < D_; k0 += 64) {
      stW(k0);
      s16x8 af0 = cvt8(abase + k0 + 8 * lg);
      s16x8 af1 = cvt8(abase + k0 + 32 + 8 * lg);
      __syncthreads();
#pragma unroll
      for (int ns = 0; ns < 4; ++ns) {
        s16x8 wf0 = WF(ns * 16 + lr, lg);
        s16x8 wf1 = WF(ns * 16 + lr, 4 + lg);
        acc[ns] = MFMA_BF16(af0, wf0, acc[ns]);
        acc[ns] = MFMA_BF16(af1, wf1, acc[ns]);
      }
      __syncthreads();
    }
#pragma unroll
    for (int ns = 0; ns < 4; ++ns) {
      int dk = ns * 16 + lr;
      float bb = bv[dk];
      u32x2 pk2;
      pk2[0] = cvtpk(acc[ns][0] + bb, acc[ns][1] + bb);
      pk2[1] = cvtpk(acc[ns][2] + bb, acc[ns][3] + bb);
      int t = s0 + w * 16 + lg * 4;
      *(u16x4*)(vst + ((size_t)b * DK_ + dk) * S_ + t) = *(u16x4*)&pk2;
    }
  }
}

// ---------------------------------------------------------------------------
// SINGLE-PASS fused scores + softmax + attn-write + PV + causal zerofill
// (r12 structure, unchanged).
// ---------------------------------------------------------------------------
__global__ __launch_bounds__(512) void attn_kernel(
    const unsigned short* __restrict__ qs, const unsigned short* __restrict__ ks,
    const unsigned short* __restrict__ vst, float* __restrict__ attn,
    unsigned short* __restrict__ hh) {
  const int m = blockIdx.x;
  const int half = m >> 8, g = (m >> 1) & 1;
  const int stp = half ? (3 - g) : g;                  // s-strip 0..3 (128 rows)
  const int rem = ((m >> 2) & 63) * 2 + (m & 1);       // 0..127
  const int b = rem & 31, h = rem >> 5;
  const int tid = threadIdx.x, w = tid >> 6, l = tid & 63;
  const int lr = l & 15, lg = l >> 4;
  const int S0 = stp * 128;
  const int dtile = 2 * stp + (w >> 2);                // this wave's diag t-tile
  const int NT = 2 * stp + 2;                          // t-tiles staged per block
  const int sg = S0 + w * 16 + lr;                     // this lane's s row (fixed)

  __shared__ __align__(16) unsigned short Kb[2][4096];   // 64x64 bf16, swizzled
  __shared__ __align__(16) unsigned short Vb[2][4096];   // [dk][t] bf16, swizzled
  __shared__ __align__(16) unsigned short Pb[8][16][72]; // per-wave P, [s][t]+pad

  const unsigned short* qb = qs + ((size_t)b * H_ + h) * S_ * DK_;
  const char* kbase = (const char*)(ks + ((size_t)b * H_ + h) * S_ * DK_);
  const char* vbase = (const char*)(vst + (size_t)b * DK_ * S_);

  auto stK = [&](int buf, int t0) {
    int p = tid * 16;
    int row = p >> 7, c = (p >> 4) & 7;
    GLOAD_LDS16(kbase + (size_t)t0 * 128 + row * 128 + ((c ^ (row & 7)) << 4),
                (char*)&Kb[buf][0] + p);
  };
  auto stV = [&](int buf, int t0) {
    int p = tid * 16;
    int row = p >> 7, c = (p >> 4) & 7;
    GLOAD_LDS16(vbase + (size_t)row * 1024 + t0 * 2 + ((c ^ (row & 7)) << 4),
                (char*)&Vb[buf][0] + p);
  };
  auto KF = [&](int buf, int row, int c) -> s16x8 {
    return *(const s16x8*)((const char*)&Kb[buf][0] + row * 128 + ((c ^ (row & 7)) << 4));
  };
  auto VF = [&](int buf, int row, int c) -> s16x8 {
    return *(const s16x8*)((const char*)&Vb[buf][0] + row * 128 + ((c ^ (row & 7)) << 4));
  };

  s16x8 qf0 = *(const s16x8*)(qb + (size_t)sg * DK_ + 8 * lg);
  s16x8 qf1 = *(const s16x8*)(qb + (size_t)sg * DK_ + 32 + 8 * lg);

  float ls[4] = {0.f, 0.f, 0.f, 0.f};
  unsigned preg[8][8];   // packed bf16 p' per tile; statically indexed
  f32x4 oacc[4] = {};

  // ---- single staged pass: QK^T once, p' packed, PV unnormalized ----
  stK(0, 0);
  stV(0, 0);
  __syncthreads();
#pragma unroll
  for (int tt = 0; tt < 8; ++tt) {
    if (tt >= NT) continue;                  // block-uniform
    const int t0 = tt * 64;
    const int cur = tt & 1;
    if (tt + 1 < NT) { stK(cur ^ 1, t0 + 64); stV(cur ^ 1, t0 + 64); }
    if (tt <= dtile) {
#pragma unroll
      for (int ts = 0; ts < 4; ++ts) {
        s16x8 kf0 = KF(cur, ts * 16 + lr, lg);
        s16x8 kf1 = KF(cur, ts * 16 + lr, 4 + lg);
        f32x4 acc = {};
        acc = MFMA_BF16(kf0, qf0, acc);   // swapped: lane holds s=lr, t=tb+i
        acc = MFMA_BF16(kf1, qf1, acc);
        const int tb = t0 + ts * 16 + 4 * lg;
        float p[4];
        if (tt == dtile) {
#pragma unroll
          for (int i = 0; i < 4; ++i) p[i] = EXP2((tb + i > sg) ? -1e30f : acc[i]);
        } else {
#pragma unroll
          for (int i = 0; i < 4; ++i) p[i] = EXP2(acc[i]);
        }
        ls[ts] += (p[0] + p[1]) + (p[2] + p[3]);
        unsigned pk0 = cvtpk(p[0], p[1]);
        unsigned pk1 = cvtpk(p[2], p[3]);
        preg[tt][ts * 2] = pk0;
        preg[tt][ts * 2 + 1] = pk1;
        *(u32x2*)&Pb[w][lr][ts * 16 + 4 * lg] = *(u32x2*)&preg[tt][ts * 2];
      }
      asm volatile("s_waitcnt lgkmcnt(0)" ::: "memory");
      __builtin_amdgcn_sched_barrier(0);
      s16x8 pa0 = *(const s16x8*)(&Pb[w][lr][8 * lg]);
      s16x8 pa1 = *(const s16x8*)(&Pb[w][lr][32 + 8 * lg]);
#pragma unroll
      for (int ds = 0; ds < 4; ++ds) {
        s16x8 vf0 = VF(cur, ds * 16 + lr, lg);
        s16x8 vf1 = VF(cur, ds * 16 + lr, 4 + lg);
        oacc[ds] = MFMA_BF16(pa0, vf0, oacc[ds]);
        oacc[ds] = MFMA_BF16(pa1, vf1, oacc[ds]);
      }
    }
    __syncthreads();
  }

  // ---- reduce row sum (lane-local row s=lr) ----
  float lsum = (ls[0] + ls[1]) + (ls[2] + ls[3]);
  lsum += __shfl_xor(lsum, 16);
  lsum += __shfl_xor(lsum, 32);
  const float inv = 1.0f / lsum;

  // ---- phase B: normalized attn writes (pure streaming, no barriers) ----
#pragma unroll
  for (int tt = 0; tt < 8; ++tt) {
    if (tt <= dtile) {
      const int t0 = tt * 64;
#pragma unroll
      for (int ts = 0; ts < 4; ++ts) {
        unsigned a = preg[tt][ts * 2], c2 = preg[tt][ts * 2 + 1];
        f32x4 p;
        p[0] = bf2f((unsigned short)a) * inv;
        p[1] = bf2f((unsigned short)(a >> 16)) * inv;
        p[2] = bf2f((unsigned short)c2) * inv;
        p[3] = bf2f((unsigned short)(c2 >> 16)) * inv;
        const int tb = t0 + ts * 16 + 4 * lg;
        *(f32x4*)(attn + (((size_t)b * S_ + sg) * H_ + h) * S_ + tb) = p;
      }
    }
  }

  // ---- causal zerofill above this wave's diagonal tile ----
  for (int tt = dtile + 1; tt < 8; ++tt) {
    const int t0 = tt * 64;
    f32x4 z = {};
#pragma unroll
    for (int i = 0; i < 4; ++i) {
      int sr = S0 + w * 16 + lg * 4 + i;
      *(f32x4*)(attn + (((size_t)b * S_ + sr) * H_ + h) * S_ + t0 + lr * 4) = z;
    }
  }

  // ---- per-head output: scale by shfl-gathered inv, write bf16 ----
  float invO[4];
#pragma unroll
  for (int i = 0; i < 4; ++i) invO[i] = __shfl(inv, lg * 4 + i);
#pragma unroll
  for (int ds = 0; ds < 4; ++ds) {
#pragma unroll
    for (int i = 0; i < 4; ++i) {
      int s = S0 + w * 16 + lg * 4 + i;
      hh[(((size_t)b * H_ + h) * S_ + s) * DK_ + ds * 16 + lr] = f2bf(oacc[ds][i] * invO[i]);
    }
  }
}

// ---------------------------------------------------------------------------
// Fused head-mean + output projection: grid (m-panel, n-half).  Each block:
// 64 rows x 128 cols, Wh half (16 KB) staged, af computed once.  512 blocks
// = 2/CU; hh read redundancy 2x (was 4x in r12, 1x but under-occupied in r13).
// ---------------------------------------------------------------------------
__global__ __launch_bounds__(256) void houtproj_kernel(
    const unsigned short* __restrict__ hh, const unsigned short* __restrict__ Whb,
    float* __restrict__ out) {
  const int m0 = blockIdx.x * 64, n0 = blockIdx.y * 128;
  const int tid = threadIdx.x, w = tid >> 6, l = tid & 63;
  const int lr = l & 15, lg = l >> 4;
  const int row = m0 + w * 16 + lr;
  const int b = row >> 9, s = row & (S_ - 1);

  __shared__ __align__(16) unsigned short Whs[8192];  // 128 x 64 bf16

#pragma unroll
  for (int it = 0; it < 4; ++it) {
    int p = it * 4096 + tid * 16;
    int r = p >> 7, c = (p >> 4) & 7;
    GLOAD_LDS16((const char*)(Whb + (size_t)(n0 + r) * DK_) + ((c ^ (r & 7)) << 4),
                (char*)Whs + p);
  }

  s16x8 af[2];
#pragma unroll
  for (int kk = 0; kk < 2; ++kk) {
    float sum8[8] = {};
#pragma unroll
    for (int hd = 0; hd < 4; ++hd) {
      s16x8 x = *(const s16x8*)(hh + (((size_t)b * H_ + hd) * S_ + s) * DK_ + kk * 32 + 8 * lg);
#pragma unroll
      for (int e = 0; e < 8; ++e) sum8[e] += bf2f((unsigned short)x[e]);
    }
    u32x4 pk;
#pragma unroll
    for (int j = 0; j < 4; ++j) pk[j] = cvtpk(sum8[2 * j], sum8[2 * j + 1]);
    af[kk] = *(s16x8*)&pk;
  }
  __syncthreads();

  auto WHF = [&](int r, int c) -> s16x8 {
    return *(const s16x8*)((const char*)Whs + r * 128 + ((c ^ (r & 7)) << 4));
  };
#pragma unroll
  for (int np = 0; np < 2; ++np) {
    f32x4 acc[4] = {};
#pragma unroll
    for (int ns = 0; ns < 4; ++ns) {
      s16x8 wf0 = WHF(np * 64 + ns * 16 + lr, lg);
      s16x8 wf1 = WHF(np * 64 + ns * 16 + lr, 4 + lg);
      acc[ns] = MFMA_BF16(af[0], wf0, acc[ns]);
      acc[ns] = MFMA_BF16(af[1], wf1, acc[ns]);
    }
#pragma unroll
    for (int ns = 0; ns < 4; ++ns) {
#pragma unroll
      for (int i = 0; i < 4; ++i) {
        out[(size_t)(m0 + w * 16 + lg * 4 + i) * D_ + n0 + np * 64 + ns * 16 + lr] = acc[ns][i];
      }
    }
  }
}

// ---------------------------------------------------------------------------
extern "C" void kernel_launch(void* const* d_in, const int* in_sizes, int n_in,
                              void* d_out, int out_size, void* d_ws, size_t ws_size,
                              hipStream_t stream) {
  (void)in_sizes; (void)n_in; (void)out_size; (void)ws_size;
  const float* q  = (const float*)d_in[0];
  const float* k  = (const float*)d_in[1];
  const float* v  = (const float*)d_in[2];
  const float* Wq = (const float*)d_in[4];
  const float* bq = (const float*)d_in[5];
  const float* Wk = (const float*)d_in[6];
  const float* bk = (const float*)d_in[7];
  const float* Wv = (const float*)d_in[8];
  const float* bv = (const float*)d_in[9];
  const float* Wh = (const float*)d_in[10];

  float* out  = (float*)d_out;                       // [B,S,D]
  float* attn = out + (size_t)B_ * S_ * D_;          // [B,S,H,S]

  char* ws = (char*)d_ws;
  unsigned short* Wb  = (unsigned short*)ws;                         // 163840 elems
  unsigned short* qs  = (unsigned short*)(ws + 327680);              // [B,H,S,DK] bf16
  unsigned short* ksp = (unsigned short*)(ws + 327680 + 8388608);    // [B,H,S,DK] bf16
  unsigned short* vst = (unsigned short*)(ws + 327680 + 16777216);   // [B,DK,S]  bf16
  unsigned short* hh  = (unsigned short*)(ws + 327680 + 18874368);   // [B,H,S,DK] bf16

  wconv_kernel<<<640, 256, 0, stream>>>(Wq, Wk, Wv, Wh, Wb);
  proj_kernel<<<dim3(256, 3), 256, 0, stream>>>(q, k, v, Wb, bq, bk, bv, qs, ksp, vst);
  attn_kernel<<<512, 512, 0, stream>>>(qs, ksp, vst, attn, hh);
  houtproj_kernel<<<dim3(256, 2), 256, 0, stream>>>(hh, Wb + 147456, out);
}

// Round 15
// 61.524 us; speedup vs baseline: 1.0762x; 1.0056x over previous
//
#include <hip/hip_runtime.h>
#include <math.h>

#define B_  32
#define S_  512
#define D_  256
#define H_  4
#define DK_ 64

typedef float  f32x4 __attribute__((ext_vector_type(4)));
typedef short  s16x8 __attribute__((ext_vector_type(8)));
typedef unsigned short u16x4 __attribute__((ext_vector_type(4)));
typedef unsigned int   u32x2 __attribute__((ext_vector_type(2)));
typedef unsigned int   u32x4 __attribute__((ext_vector_type(4)));

#define MFMA_BF16(a, b, c) __builtin_amdgcn_mfma_f32_16x16x32_bf16((a), (b), (c), 0, 0, 0)
#define GLOAD_LDS16(g, l)                                                      \
  __builtin_amdgcn_global_load_lds(                                            \
      (const __attribute__((address_space(1))) void*)(g),                      \
      (__attribute__((address_space(3))) void*)(l), 16, 0, 0)

#if __has_builtin(__builtin_amdgcn_exp2f)
#define EXP2(x) __builtin_amdgcn_exp2f(x)
#else
#define EXP2(x) __expf((x) * 0.6931471805599453f)
#endif

// 0.125 * log2(e): folded into Wq/bq so QK^T lands in log2 domain.
#define QSCALE 0.18033688011112042f

__device__ __forceinline__ unsigned short f2bf(float x) {
  unsigned int u = __float_as_uint(x);
  unsigned int r = (u + 0x7FFFu + ((u >> 16) & 1u)) >> 16;
  return (unsigned short)r;
}

__device__ __forceinline__ float bf2f(unsigned short u) {
  return __uint_as_float((unsigned int)u << 16);
}

__device__ __forceinline__ unsigned cvtpk(float lo, float hi) {
  unsigned r;
  asm("v_cvt_pk_bf16_f32 %0, %1, %2" : "=v"(r) : "v"(lo), "v"(hi));
  return r;
}

// f32x8 -> bf16x8 via 4 cvt_pk (replaces 16 manual-RNE f2bf ops)
__device__ __forceinline__ s16x8 cvt8(const float* p) {
  float4 a = *(const float4*)p;
  float4 b = *(const float4*)(p + 4);
  u32x4 pk;
  pk[0] = cvtpk(a.x, a.y);
  pk[1] = cvtpk(a.z, a.w);
  pk[2] = cvtpk(b.x, b.y);
  pk[3] = cvtpk(b.z, b.w);
  return *(s16x8*)&pk;
}

// ---------------------------------------------------------------------------
// Weights -> bf16: rows 0..255 Wq (pre-scaled by QSCALE), 256..511 Wk,
// 512..575 Wv; Wh at 147456 (pre-scaled by 0.25 for the head-mean fold).
// ---------------------------------------------------------------------------
__global__ void wconv_kernel(const float* __restrict__ Wq, const float* __restrict__ Wk,
                             const float* __restrict__ Wv, const float* __restrict__ Wh,
                             unsigned short* __restrict__ out) {
  int i = blockIdx.x * 256 + threadIdx.x;  // 163840 total
  float v, sc = 1.f;
  if (i < 65536)        { v = Wq[i];          sc = QSCALE; }
  else if (i < 131072)  { v = Wk[i - 65536]; }
  else if (i < 147456)  { v = Wv[i - 131072]; }
  else                  { v = Wh[i - 147456]; sc = 0.25f; }
  out[i] = f2bf(v * sc);
}

// ---------------------------------------------------------------------------
// Fused QKV projection, bf16 MFMA, W k-slice staged in LDS (r14 structure).
// ---------------------------------------------------------------------------
__global__ __launch_bounds__(256) void proj_kernel(
    const float* __restrict__ q, const float* __restrict__ k, const float* __restrict__ v,
    const unsigned short* __restrict__ Wb,
    const float* __restrict__ bq, const float* __restrict__ bk, const float* __restrict__ bv,
    unsigned short* __restrict__ qs, unsigned short* __restrict__ ks,
    unsigned short* __restrict__ vst) {
  const int y = blockIdx.y;
  const int m0 = blockIdx.x * 64;
  const int b = m0 >> 9, s0 = m0 & (S_ - 1);
  const int tid = threadIdx.x, w = tid >> 6, l = tid & 63;
  const int lr = l & 15, lg = l >> 4;
  const float* src = (y == 0) ? q : (y == 1) ? k : v;
  const float* abase = src + (size_t)(m0 + w * 16 + lr) * D_;

  __shared__ __align__(16) unsigned short Wsl[16384];  // up to 256 rows x 64 cols bf16

  const int nrows = (y < 2) ? 256 : 64;
  const unsigned short* wbase = Wb + (size_t)(y * 256) * D_;  // y==2 -> rows 512.. (Wv)

  auto stW = [&](int k0) {
    const int nbytes = nrows * 128;
    for (int p = tid * 16; p < nbytes; p += 4096) {
      int row = p >> 7, c = (p >> 4) & 7;
      GLOAD_LDS16((const char*)(wbase + (size_t)row * D_ + k0) + ((c ^ (row & 7)) << 4),
                  (char*)Wsl + p);
    }
  };
  auto WF = [&](int row, int c) -> s16x8 {
    return *(const s16x8*)((const char*)Wsl + row * 128 + ((c ^ (row & 7)) << 4));
  };

  if (y < 2) {
    f32x4 acc[4][4] = {};
    for (int k0 = 0; k0 < D_; k0 += 64) {
      stW(k0);
      s16x8 af0 = cvt8(abase + k0 + 8 * lg);
      s16x8 af1 = cvt8(abase + k0 + 32 + 8 * lg);
      __syncthreads();
#pragma unroll
      for (int h = 0; h < 4; ++h) {
#pragma unroll
        for (int ns = 0; ns < 4; ++ns) {
          s16x8 wf0 = WF(h * 64 + ns * 16 + lr, lg);
          s16x8 wf1 = WF(h * 64 + ns * 16 + lr, 4 + lg);
          acc[h][ns] = MFMA_BF16(af0, wf0, acc[h][ns]);
          acc[h][ns] = MFMA_BF16(af1, wf1, acc[h][ns]);
        }
      }
      __syncthreads();
    }
    const float* bias = (y == 0) ? bq : bk;
    const float bsc = (y == 0) ? QSCALE : 1.f;
    unsigned short* dst = (y == 0) ? qs : ks;
#pragma unroll
    for (int h = 0; h < 4; ++h) {
#pragma unroll
      for (int ns = 0; ns < 4; ++ns) {
        int dk = ns * 16 + lr;
        float bb = bias[h * 64 + dk] * bsc;
        unsigned u0 = cvtpk(acc[h][ns][0] + bb, acc[h][ns][1] + bb);
        unsigned u1 = cvtpk(acc[h][ns][2] + bb, acc[h][ns][3] + bb);
        size_t base = (((size_t)b * H_ + h) * S_ + s0 + w * 16 + lg * 4) * DK_ + dk;
        dst[base]            = (unsigned short)u0;
        dst[base + DK_]      = (unsigned short)(u0 >> 16);
        dst[base + 2 * DK_]  = (unsigned short)u1;
        dst[base + 3 * DK_]  = (unsigned short)(u1 >> 16);
      }
    }
  } else {
    f32x4 acc[4] = {};
    for (int k0 = 0; k0 < D_; k0 += 64) {
      stW(k0);
      s16x8 af0 = cvt8(abase + k0 + 8 * lg);
      s16x8 af1 = cvt8(abase + k0 + 32 + 8 * lg);
      __syncthreads();
#pragma unroll
      for (int ns = 0; ns < 4; ++ns) {
        s16x8 wf0 = WF(ns * 16 + lr, lg);
        s16x8 wf1 = WF(ns * 16 + lr, 4 + lg);
        acc[ns] = MFMA_BF16(af0, wf0, acc[ns]);
        acc[ns] = MFMA_BF16(af1, wf1, acc[ns]);
      }
      __syncthreads();
    }
#pragma unroll
    for (int ns = 0; ns < 4; ++ns) {
      int dk = ns * 16 + lr;
      float bb = bv[dk];
      u32x2 pk2;
      pk2[0] = cvtpk(acc[ns][0] + bb, acc[ns][1] + bb);
      pk2[1] = cvtpk(acc[ns][2] + bb, acc[ns][3] + bb);
      int t = s0 + w * 16 + lg * 4;
      *(u16x4*)(vst + ((size_t)b * DK_ + dk) * S_ + t) = *(u16x4*)&pk2;
    }
  }
}

// ---------------------------------------------------------------------------
// SINGLE-PASS fused scores + softmax + attn-write + PV + causal zerofill.
// r14 structure; NEW: zerofill hoisted to kernel start (issued after the
// first stage instructions, before the first barrier) so the zero-write
// stream overlaps the compute/stage phase instead of bunching at the end.
// ---------------------------------------------------------------------------
__global__ __launch_bounds__(512) void attn_kernel(
    const unsigned short* __restrict__ qs, const unsigned short* __restrict__ ks,
    const unsigned short* __restrict__ vst, float* __restrict__ attn,
    unsigned short* __restrict__ hh) {
  const int m = blockIdx.x;
  const int half = m >> 8, g = (m >> 1) & 1;
  const int stp = half ? (3 - g) : g;                  // s-strip 0..3 (128 rows)
  const int rem = ((m >> 2) & 63) * 2 + (m & 1);       // 0..127
  const int b = rem & 31, h = rem >> 5;
  const int tid = threadIdx.x, w = tid >> 6, l = tid & 63;
  const int lr = l & 15, lg = l >> 4;
  const int S0 = stp * 128;
  const int dtile = 2 * stp + (w >> 2);                // this wave's diag t-tile
  const int NT = 2 * stp + 2;                          // t-tiles staged per block
  const int sg = S0 + w * 16 + lr;                     // this lane's s row (fixed)

  __shared__ __align__(16) unsigned short Kb[2][4096];   // 64x64 bf16, swizzled
  __shared__ __align__(16) unsigned short Vb[2][4096];   // [dk][t] bf16, swizzled
  __shared__ __align__(16) unsigned short Pb[8][16][72]; // per-wave P, [s][t]+pad

  const unsigned short* qb = qs + ((size_t)b * H_ + h) * S_ * DK_;
  const char* kbase = (const char*)(ks + ((size_t)b * H_ + h) * S_ * DK_);
  const char* vbase = (const char*)(vst + (size_t)b * DK_ * S_);

  auto stK = [&](int buf, int t0) {
    int p = tid * 16;
    int row = p >> 7, c = (p >> 4) & 7;
    GLOAD_LDS16(kbase + (size_t)t0 * 128 + row * 128 + ((c ^ (row & 7)) << 4),
                (char*)&Kb[buf][0] + p);
  };
  auto stV = [&](int buf, int t0) {
    int p = tid * 16;
    int row = p >> 7, c = (p >> 4) & 7;
    GLOAD_LDS16(vbase + (size_t)row * 1024 + t0 * 2 + ((c ^ (row & 7)) << 4),
                (char*)&Vb[buf][0] + p);
  };
  auto KF = [&](int buf, int row, int c) -> s16x8 {
    return *(const s16x8*)((const char*)&Kb[buf][0] + row * 128 + ((c ^ (row & 7)) << 4));
  };
  auto VF = [&](int buf, int row, int c) -> s16x8 {
    return *(const s16x8*)((const char*)&Vb[buf][0] + row * 128 + ((c ^ (row & 7)) << 4));
  };

  s16x8 qf0 = *(const s16x8*)(qb + (size_t)sg * DK_ + 8 * lg);
  s16x8 qf1 = *(const s16x8*)(qb + (size_t)sg * DK_ + 32 + 8 * lg);

  float ls[4] = {0.f, 0.f, 0.f, 0.f};
  unsigned preg[8][8];   // packed bf16 p' per tile; statically indexed
  f32x4 oacc[4] = {};

  // ---- stage tile 0, then issue the (independent) causal zerofill early so
  //      its stores overlap the whole compute phase ----
  stK(0, 0);
  stV(0, 0);
  for (int tt = dtile + 1; tt < 8; ++tt) {
    const int t0 = tt * 64;
    f32x4 z = {};
#pragma unroll
    for (int i = 0; i < 4; ++i) {
      int sr = S0 + w * 16 + lg * 4 + i;
      *(f32x4*)(attn + (((size_t)b * S_ + sr) * H_ + h) * S_ + t0 + lr * 4) = z;
    }
  }
  __syncthreads();

  // ---- single staged pass: QK^T once, p' packed, PV unnormalized ----
#pragma unroll
  for (int tt = 0; tt < 8; ++tt) {
    if (tt >= NT) continue;                  // block-uniform
    const int t0 = tt * 64;
    const int cur = tt & 1;
    if (tt + 1 < NT) { stK(cur ^ 1, t0 + 64); stV(cur ^ 1, t0 + 64); }
    if (tt <= dtile) {
#pragma unroll
      for (int ts = 0; ts < 4; ++ts) {
        s16x8 kf0 = KF(cur, ts * 16 + lr, lg);
        s16x8 kf1 = KF(cur, ts * 16 + lr, 4 + lg);
        f32x4 acc = {};
        acc = MFMA_BF16(kf0, qf0, acc);   // swapped: lane holds s=lr, t=tb+i
        acc = MFMA_BF16(kf1, qf1, acc);
        const int tb = t0 + ts * 16 + 4 * lg;
        float p[4];
        if (tt == dtile) {
#pragma unroll
          for (int i = 0; i < 4; ++i) p[i] = EXP2((tb + i > sg) ? -1e30f : acc[i]);
        } else {
#pragma unroll
          for (int i = 0; i < 4; ++i) p[i] = EXP2(acc[i]);
        }
        ls[ts] += (p[0] + p[1]) + (p[2] + p[3]);
        unsigned pk0 = cvtpk(p[0], p[1]);
        unsigned pk1 = cvtpk(p[2], p[3]);
        preg[tt][ts * 2] = pk0;
        preg[tt][ts * 2 + 1] = pk1;
        *(u32x2*)&Pb[w][lr][ts * 16 + 4 * lg] = *(u32x2*)&preg[tt][ts * 2];
      }
      asm volatile("s_waitcnt lgkmcnt(0)" ::: "memory");
      __builtin_amdgcn_sched_barrier(0);
      s16x8 pa0 = *(const s16x8*)(&Pb[w][lr][8 * lg]);
      s16x8 pa1 = *(const s16x8*)(&Pb[w][lr][32 + 8 * lg]);
#pragma unroll
      for (int ds = 0; ds < 4; ++ds) {
        s16x8 vf0 = VF(cur, ds * 16 + lr, lg);
        s16x8 vf1 = VF(cur, ds * 16 + lr, 4 + lg);
        oacc[ds] = MFMA_BF16(pa0, vf0, oacc[ds]);
        oacc[ds] = MFMA_BF16(pa1, vf1, oacc[ds]);
      }
    }
    __syncthreads();
  }

  // ---- reduce row sum (lane-local row s=lr) ----
  float lsum = (ls[0] + ls[1]) + (ls[2] + ls[3]);
  lsum += __shfl_xor(lsum, 16);
  lsum += __shfl_xor(lsum, 32);
  const float inv = 1.0f / lsum;

  // ---- phase B: normalized attn writes (pure streaming, no barriers) ----
#pragma unroll
  for (int tt = 0; tt < 8; ++tt) {
    if (tt <= dtile) {
      const int t0 = tt * 64;
#pragma unroll
      for (int ts = 0; ts < 4; ++ts) {
        unsigned a = preg[tt][ts * 2], c2 = preg[tt][ts * 2 + 1];
        f32x4 p;
        p[0] = bf2f((unsigned short)a) * inv;
        p[1] = bf2f((unsigned short)(a >> 16)) * inv;
        p[2] = bf2f((unsigned short)c2) * inv;
        p[3] = bf2f((unsigned short)(c2 >> 16)) * inv;
        const int tb = t0 + ts * 16 + 4 * lg;
        *(f32x4*)(attn + (((size_t)b * S_ + sg) * H_ + h) * S_ + tb) = p;
      }
    }
  }

  // ---- per-head output: scale by shfl-gathered inv, write bf16 ----
  float invO[4];
#pragma unroll
  for (int i = 0; i < 4; ++i) invO[i] = __shfl(inv, lg * 4 + i);
#pragma unroll
  for (int ds = 0; ds < 4; ++ds) {
#pragma unroll
    for (int i = 0; i < 4; ++i) {
      int s = S0 + w * 16 + lg * 4 + i;
      hh[(((size_t)b * H_ + h) * S_ + s) * DK_ + ds * 16 + lr] = f2bf(oacc[ds][i] * invO[i]);
    }
  }
}

// ---------------------------------------------------------------------------
// Fused head-mean + output projection: grid (m-panel, n-half) as r14.
// ---------------------------------------------------------------------------
__global__ __launch_bounds__(256) void houtproj_kernel(
    const unsigned short* __restrict__ hh, const unsigned short* __restrict__ Whb,
    float* __restrict__ out) {
  const int m0 = blockIdx.x * 64, n0 = blockIdx.y * 128;
  const int tid = threadIdx.x, w = tid >> 6, l = tid & 63;
  const int lr = l & 15, lg = l >> 4;
  const int row = m0 + w * 16 + lr;
  const int b = row >> 9, s = row & (S_ - 1);

  __shared__ __align__(16) unsigned short Whs[8192];  // 128 x 64 bf16

#pragma unroll
  for (int it = 0; it < 4; ++it) {
    int p = it * 4096 + tid * 16;
    int r = p >> 7, c = (p >> 4) & 7;
    GLOAD_LDS16((const char*)(Whb + (size_t)(n0 + r) * DK_) + ((c ^ (r & 7)) << 4),
                (char*)Whs + p);
  }

  s16x8 af[2];
#pragma unroll
  for (int kk = 0; kk < 2; ++kk) {
    float sum8[8] = {};
#pragma unroll
    for (int hd = 0; hd < 4; ++hd) {
      s16x8 x = *(const s16x8*)(hh + (((size_t)b * H_ + hd) * S_ + s) * DK_ + kk * 32 + 8 * lg);
#pragma unroll
      for (int e = 0; e < 8; ++e) sum8[e] += bf2f((unsigned short)x[e]);
    }
    u32x4 pk;
#pragma unroll
    for (int j = 0; j < 4; ++j) pk[j] = cvtpk(sum8[2 * j], sum8[2 * j + 1]);
    af[kk] = *(s16x8*)&pk;
  }
  __syncthreads();

  auto WHF = [&](int r, int c) -> s16x8 {
    return *(const s16x8*)((const char*)Whs + r * 128 + ((c ^ (r & 7)) << 4));
  };
#pragma unroll
  for (int np = 0; np < 2; ++np) {
    f32x4 acc[4] = {};
#pragma unroll
    for (int ns = 0; ns < 4; ++ns) {
      s16x8 wf0 = WHF(np * 64 + ns * 16 + lr, lg);
      s16x8 wf1 = WHF(np * 64 + ns * 16 + lr, 4 + lg);
      acc[ns] = MFMA_BF16(af[0], wf0, acc[ns]);
      acc[ns] = MFMA_BF16(af[1], wf1, acc[ns]);
    }
#pragma unroll
    for (int ns = 0; ns < 4; ++ns) {
#pragma unroll
      for (int i = 0; i < 4; ++i) {
        out[(size_t)(m0 + w * 16 + lg * 4 + i) * D_ + n0 + np * 64 + ns * 16 + lr] = acc[ns][i];
      }
    }
  }
}

// ---------------------------------------------------------------------------
extern "C" void kernel_launch(void* const* d_in, const int* in_sizes, int n_in,
                              void* d_out, int out_size, void* d_ws, size_t ws_size,
                              hipStream_t stream) {
  (void)in_sizes; (void)n_in; (void)out_size; (void)ws_size;
  const float* q  = (const float*)d_in[0];
  const float* k  = (const float*)d_in[1];
  const float* v  = (const float*)d_in[2];
  const float* Wq = (const float*)d_in[4];
  const float* bq = (const float*)d_in[5];
  const float* Wk = (const float*)d_in[6];
  const float* bk = (const float*)d_in[7];
  const float* Wv = (const float*)d_in[8];
  const float* bv = (const float*)d_in[9];
  const float* Wh = (const float*)d_in[10];

  float* out  = (float*)d_out;                       // [B,S,D]
  float* attn = out + (size_t)B_ * S_ * D_;          // [B,S,H,S]

  char* ws = (char*)d_ws;
  unsigned short* Wb  = (unsigned short*)ws;                         // 163840 elems
  unsigned short* qs  = (unsigned short*)(ws + 327680);              // [B,H,S,DK] bf16
  unsigned short* ksp = (unsigned short*)(ws + 327680 + 8388608);    // [B,H,S,DK] bf16
  unsigned short* vst = (unsigned short*)(ws + 327680 + 16777216);   // [B,DK,S]  bf16
  unsigned short* hh  = (unsigned short*)(ws + 327680 + 18874368);   // [B,H,S,DK] bf16

  wconv_kernel<<<640, 256, 0, stream>>>(Wq, Wk, Wv, Wh, Wb);
  proj_kernel<<<dim3(256, 3), 256, 0, stream>>>(q, k, v, Wb, bq, bk, bv, qs, ksp, vst);
  attn_kernel<<<512, 512, 0, stream>>>(qs, ksp, vst, attn, hh);
  houtproj_kernel<<<dim3(256, 2), 256, 0, stream>>>(hh, Wb + 147456, out);
}